// Round 5
// baseline (895.828 us; speedup 1.0000x reference)
//
#include <hip/hip_runtime.h>
#include <hip/hip_bf16.h>

// Problem constants (N=64, D=64, H=64, W=64, K=512)
#define VQ_D   64
#define VQ_K   512
#define VQ_HW  4096
#define VQ_M   262144
#define VQ_LOSS_OFF 16777216
#define VQ_IDX_OFF  16777217
#define VQ_MARGIN   4.5e-4f
#define VQ_BIAS     0.25f

typedef __bf16 bf16x8v __attribute__((ext_vector_type(8)));
typedef float  f32x16  __attribute__((ext_vector_type(16)));

union BF8 { unsigned short u[8]; uint4 q4; bf16x8v v; };

// fp32 -> bf16 round-to-nearest-even
__device__ __forceinline__ unsigned short f2bf(float f) {
    unsigned u = __builtin_bit_cast(unsigned, f);
    u += 0x7FFFu + ((u >> 16) & 1u);
    return (unsigned short)(u >> 16);
}

// ---------------------------------------------------------------------------
// Prep: esq[k] (numpy pairwise, bitwise-exact), A-fragments for the
// TRANSPOSED screen (codes as M-dim), and zero loss/cnt.
// A-frag (32x32x16, tile t, quarter q): lane l holds A[m=l&31][k=(l>>5)*8+j].
//   q<4 : bf16(-2 * emb[code][q*16 + k])
//   q==4: k=0 -> bf16_hi(0.25+esq), k=1 -> bf16_lo, else 0   (B there = 1,1,0..)
// => acc = 0.25 + esq - 2*dot  (positive => uint-comparable)
// ---------------------------------------------------------------------------
__global__ void vq_prep(const float* __restrict__ emb, float* __restrict__ esq,
                        uint4* __restrict__ kfrag,
                        double* __restrict__ loss_acc, int* __restrict__ cnt) {
#pragma clang fp contract(off)
    int k = blockIdx.x * 256 + threadIdx.x;
    if (k == 0) { *loss_acc = 0.0; *cnt = 0; }
    if (k < VQ_K) {
        const float* e = emb + k * VQ_D;
        float p[VQ_D];
#pragma unroll
        for (int d = 0; d < VQ_D; ++d) p[d] = e[d] * e[d];
        float r[8];
#pragma unroll
        for (int j = 0; j < 8; ++j) r[j] = p[j];
#pragma unroll
        for (int i = 8; i < VQ_D; i += 8)
#pragma unroll
            for (int j = 0; j < 8; ++j) r[j] += p[i + j];
        float es = ((r[0] + r[1]) + (r[2] + r[3])) + ((r[4] + r[5]) + (r[6] + r[7]));
        esq[k] = es;

        float sc = VQ_BIAS + es;
        unsigned short hi = f2bf(sc);
        float hif = __builtin_bit_cast(float, ((unsigned)hi) << 16);
        unsigned short lo = f2bf(sc - hif);

        int t = k >> 5, c = k & 31;
#pragma unroll
        for (int q = 0; q < 4; ++q)
#pragma unroll
            for (int h = 0; h < 2; ++h) {
                BF8 tmp;
#pragma unroll
                for (int j = 0; j < 8; ++j)
                    tmp.u[j] = f2bf(-2.0f * e[q * 16 + h * 8 + j]);
                kfrag[(t * 5 + q) * 64 + h * 32 + c] = tmp.q4;
            }
        BF8 t4;
#pragma unroll
        for (int j = 0; j < 8; ++j) t4.u[j] = 0;
        t4.u[0] = hi; t4.u[1] = lo;
        kfrag[(t * 5 + 4) * 64 + c] = t4.q4;           // half 0
        BF8 t5;
#pragma unroll
        for (int j = 0; j < 8; ++j) t5.u[j] = 0;
        kfrag[(t * 5 + 4) * 64 + 32 + c] = t5.q4;      // half 1
    }
}

// ---------------------------------------------------------------------------
// Screen + fused output. Block = 512 thr (8 waves); each wave owns 32 points
// (one B-column group). Per k-tile of 32 codes: 5 MFMAs -> 16 scores/lane
// (for the lane's point). Packed-key top-2 (2 regs), xor-32 merge, write
// z_q/loss for unflagged, append flagged to list.
// ---------------------------------------------------------------------------
__global__ __launch_bounds__(512) void vq_screen(
        const float* __restrict__ z_e,
        const uint4* __restrict__ kfrag,
        const float* __restrict__ emb,
        float* __restrict__ out,
        float* __restrict__ out_idx,
        int* __restrict__ cnt,
        int* __restrict__ flag_list,
        double* __restrict__ loss_acc)
{
    __shared__ uint4 smem[2560];                       // 40 KB: 8 tiles x 5 q
    const int tid = threadIdx.x;
    const int w   = tid >> 6;
    const int l   = tid & 63;
    const int c   = l & 31;                            // point column
    const int h   = l >> 5;

    const int m0 = (blockIdx.x * 8 + w) * 32;          // 32 points, same n
    const int n  = m0 >> 12;
    const int hw = (m0 & 4095) + c;
    const float* zb = z_e + (size_t)n * (VQ_D * VQ_HW) + hw;

    // z fp32 (kept for epilogue) + bf16 B-frags. d = q*16 + h*8 + j.
    float zf[32];
#pragma unroll
    for (int q = 0; q < 4; ++q)
#pragma unroll
        for (int j = 0; j < 8; ++j)
            zf[q * 8 + j] = zb[(q * 16 + h * 8 + j) * VQ_HW];
    bf16x8v bz[4];
#pragma unroll
    for (int q = 0; q < 4; ++q) {
        BF8 tmp;
#pragma unroll
        for (int j = 0; j < 8; ++j) tmp.u[j] = f2bf(zf[q * 8 + j]);
        bz[q] = tmp.v;
    }
    BF8 tob;
#pragma unroll
    for (int j = 0; j < 8; ++j) tob.u[j] = 0;
    if (h == 0) { tob.u[0] = 0x3F80; tob.u[1] = 0x3F80; }   // B = (1,1,0,..)
    const bf16x8v bones = tob.v;

    int coder[16];
#pragma unroll
    for (int r = 0; r < 16; ++r) coder[r] = (r & 3) + 8 * (r >> 2) + 4 * h;

    unsigned m1 = 0xFFFFFFFFu, m2 = 0xFFFFFFFFu;
    const unsigned SMASK = 0xFFFFFE00u;

    for (int ht = 0; ht < 2; ++ht) {                   // two 8-tile halves
        if (ht) __syncthreads();
#pragma unroll
        for (int i = 0; i < 5; ++i)
            smem[i * 512 + tid] = kfrag[ht * 2560 + i * 512 + tid];
        __syncthreads();

        for (int t8 = 0; t8 < 8; ++t8) {
            f32x16 acc;
#pragma unroll
            for (int r = 0; r < 16; ++r) acc[r] = 0.f;
#pragma unroll
            for (int q = 0; q < 4; ++q) {
                bf16x8v a = __builtin_bit_cast(bf16x8v, smem[(t8 * 5 + q) * 64 + l]);
                acc = __builtin_amdgcn_mfma_f32_32x32x16_bf16(a, bz[q], acc, 0, 0, 0);
            }
            bf16x8v a4 = __builtin_bit_cast(bf16x8v, smem[(t8 * 5 + 4) * 64 + l]);
            acc = __builtin_amdgcn_mfma_f32_32x32x16_bf16(a4, bones, acc, 0, 0, 0);

#pragma unroll
            for (int r = 0; r < 16; ++r) {
                unsigned key = (__builtin_bit_cast(unsigned, acc[r]) & SMASK)
                               | (unsigned)coder[r];
                unsigned mx = m1 > key ? m1 : key;
                m2 = m2 < mx ? m2 : mx;
                m1 = m1 < key ? m1 : key;
                coder[r] += 32;
            }
        }
    }

    // merge the two halves of the code range (lane ^ 32)
    unsigned om1 = (unsigned)__shfl_xor((int)m1, 32, 64);
    unsigned om2 = (unsigned)__shfl_xor((int)m2, 32, 64);
    unsigned mx  = m1 > om1 ? m1 : om1;
    m1 = m1 < om1 ? m1 : om1;
    m2 = m2 < om2 ? m2 : om2;
    m2 = m2 < mx ? m2 : mx;

    const int   win = (int)(m1 & 511u);
    const float s1  = __builtin_bit_cast(float, m1 & SMASK);
    const float s2  = __builtin_bit_cast(float, m2 & SMASK);
    const bool  flagged = (s2 - s1) <= VQ_MARGIN;

    if (h == 0) out_idx[m0 + c] = (float)win;

    // compact flagged points (lanes 0..31 represent the 32 points)
    unsigned long long bal = __ballot(flagged);
    unsigned mask32 = (unsigned)(bal & 0xFFFFFFFFull);
    int cw = __popc(mask32);
    int basepos = 0;
    if (l == 0 && cw) basepos = atomicAdd(cnt, cw);
    basepos = __shfl(basepos, 0, 64);
    if (h == 0 && flagged)
        flag_list[basepos + __popc(mask32 & ((1u << c) - 1u))] = m0 + c;

    // fused z_q + loss for unflagged points (rescore handles flagged fully)
    float lsum = 0.f;
    if (!flagged) {
        const float* er = emb + (win << 6);
        float* op = out + (size_t)n * (VQ_D * VQ_HW) + hw;
#pragma unroll
        for (int q = 0; q < 4; ++q) {
            const float* eb = er + q * 16 + h * 8;
            float4 ea = *(const float4*)eb;
            float4 e2 = *(const float4*)(eb + 4);
            float ev[8] = {ea.x, ea.y, ea.z, ea.w, e2.x, e2.y, e2.z, e2.w};
#pragma unroll
            for (int j = 0; j < 8; ++j) {
                op[(q * 16 + h * 8 + j) * VQ_HW] = ev[j];
                float df = zf[q * 8 + j] - ev[j];
                lsum = fmaf(df, df, lsum);
            }
        }
    }
    for (int off = 32; off > 0; off >>= 1)
        lsum += __shfl_down(lsum, off, 64);
    if (l == 0) atomicAdd(loss_acc, (double)lsum);
}

// ---------------------------------------------------------------------------
// Rescore: thread per flagged point, bitwise round-3 math, codebook staged
// through LDS in two 64 KB halves (wave-uniform broadcast ds_reads).
// Writes idx + z_q row + loss contribution for every flagged point.
// ---------------------------------------------------------------------------
__global__ __launch_bounds__(256) void vq_rescore(
        const float* __restrict__ z_e,
        const float* __restrict__ emb,
        const float* __restrict__ esq,
        float* __restrict__ out,
        float* __restrict__ out_idx,
        const int* __restrict__ cnt,
        const int* __restrict__ flag_list,
        double* __restrict__ loss_acc)
{
#pragma clang fp contract(off)
    extern __shared__ float lut[];                     // 64 KB: 256 rows
    const int tid = threadIdx.x;
    const int total = *cnt;
    if ((int)blockIdx.x * 256 >= total) return;

    const int  i   = blockIdx.x * 256 + tid;
    const bool act = i < total;
    const int  m   = flag_list[act ? i : 0];
    const int  n   = m >> 12;
    const int  hw  = m & 4095;

    const float* zp = z_e + (size_t)n * (VQ_D * VQ_HW) + hw;
    float z[VQ_D];
#pragma unroll
    for (int d = 0; d < VQ_D; ++d) z[d] = zp[d * VQ_HW];

    float p[VQ_D];
#pragma unroll
    for (int d = 0; d < VQ_D; ++d) p[d] = z[d] * z[d];
    float r[8];
#pragma unroll
    for (int j = 0; j < 8; ++j) r[j] = p[j];
#pragma unroll
    for (int ii = 8; ii < VQ_D; ii += 8)
#pragma unroll
        for (int j = 0; j < 8; ++j) r[j] += p[ii + j];
    const float zsq = ((r[0] + r[1]) + (r[2] + r[3])) + ((r[4] + r[5]) + (r[6] + r[7]));

    float best = 3.4e38f;
    int   bi   = 0;
    for (int ht = 0; ht < 2; ++ht) {
        if (ht) __syncthreads();
        const float4* src = (const float4*)(emb + ht * 256 * VQ_D);
        float4* dst = (float4*)lut;
        for (int j = tid; j < 4096; j += 256) dst[j] = src[j];
        __syncthreads();
        for (int kk = 0; kk < 256; kk += 2) {
            const float* e0 = lut + kk * VQ_D;
            const float* e1 = e0 + VQ_D;
            float a0 = 0.f, a1 = 0.f;
#pragma unroll
            for (int d = 0; d < VQ_D; ++d) {
                a0 = __builtin_fmaf(z[d], e0[d], a0);
                a1 = __builtin_fmaf(z[d], e1[d], a1);
            }
            const int k = ht * 256 + kk;
            float d0 = (zsq + esq[k])     - 2.0f * a0;
            float d1 = (zsq + esq[k + 1]) - 2.0f * a1;
            if (d0 < best) { best = d0; bi = k; }
            if (d1 < best) { best = d1; bi = k + 1; }
        }
    }

    float lsum = 0.f;
    if (act) {
        out_idx[m] = (float)bi;
        const float* er = emb + bi * VQ_D;
        float* op = out + (size_t)n * (VQ_D * VQ_HW) + hw;
#pragma unroll
        for (int d = 0; d < VQ_D; ++d) {
            float q = er[d];
            op[d * VQ_HW] = q;
            float df = z[d] - q;
            lsum = __builtin_fmaf(df, df, lsum);
        }
    }
    for (int off = 32; off > 0; off >>= 1)
        lsum += __shfl_down(lsum, off, 64);
    if ((tid & 63) == 0) atomicAdd(loss_acc, (double)lsum);
}

__global__ void vq_fin(const double* __restrict__ loss_acc, float* __restrict__ out) {
    if (threadIdx.x == 0)
        out[VQ_LOSS_OFF] = (float)(*loss_acc / 16777216.0);
}

extern "C" void kernel_launch(void* const* d_in, const int* in_sizes, int n_in,
                              void* d_out, int out_size, void* d_ws, size_t ws_size,
                              hipStream_t stream) {
    const float* z_e = (const float*)d_in[0];
    const float* emb = (const float*)d_in[1];
    float* out = (float*)d_out;
    float* out_idx = out + VQ_IDX_OFF;

    // ws layout:
    //   0     : double loss_acc                  (8 B)
    //   8     : int cnt                          (4 B + pad)
    //   16    : float esq[512]                   (2048 B)  -> 2064
    //   2064  : uint4 kfrag[5120]                (81920 B) -> 83984 (16-aligned)
    //   83984 : int flag_list[262144]            (1 MB)
    char* ws = (char*)d_ws;
    double* loss_acc = (double*)ws;
    int*    cnt      = (int*)(ws + 8);
    float*  esq      = (float*)(ws + 16);
    uint4*  kfrag    = (uint4*)(ws + 2064);
    int*    flag_list= (int*)(ws + 83984);

    vq_prep<<<2, 256, 0, stream>>>(emb, esq, kfrag, loss_acc, cnt);
    vq_screen<<<VQ_M / 256, 512, 0, stream>>>(z_e, kfrag, emb, out, out_idx,
                                              cnt, flag_list, loss_acc);
    vq_rescore<<<VQ_M / 256, 256, 65536, stream>>>(z_e, emb, esq, out, out_idx,
                                                   cnt, flag_list, loss_acc);
    vq_fin<<<1, 64, 0, stream>>>(loss_acc, out);
}